// Round 1
// baseline (1152.671 us; speedup 1.0000x reference)
//
#include <hip/hip_runtime.h>
#include <cstdint>

// Problem constants (from reference)
#define TSEQ 224
#define HID 128
#define G4 512              // 4*HID gates
#define NSEQ 1280           // BATCHES*SUB = 64*20
#define KTOT (TSEQ*HID)     // 28672
#define NT 16               // sequences per GEMM1 block
#define KSPLIT 8            // K-split for GEMM1
#define KCH 128             // K staging chunk
#define KPB (KTOT/KSPLIT)   // 3584

// ---------------------------------------------------------------------------
// LSTM: one block per sequence, 512 threads (thread g owns gate g, W_hh row g
// resident in 128 VGPRs). Early-exits at ragged len; zero-fills hs tail.
// ---------------------------------------------------------------------------
__global__ __launch_bounds__(512) void lstm_kernel(
    const float* __restrict__ x,      // [NSEQ, TSEQ]
    const float* __restrict__ W_ih,   // [512, 1]
    const float* __restrict__ W_hh,   // [512, 128]
    const float* __restrict__ b_ih,   // [512]
    const float* __restrict__ b_hh,   // [512]
    float* __restrict__ hs)           // [NSEQ, TSEQ, HID]
{
  const int n = blockIdx.x;
  const int g = threadIdx.x;

  __shared__ float s_x[TSEQ];
  __shared__ float s_h[HID];
  __shared__ float s_g[G4];
  __shared__ int   s_fz;

  // W_hh row g -> registers (one-time, L2-hot after first blocks)
  float w[HID];
  {
    const float4* wr = (const float4*)(W_hh + (size_t)g * HID);
    #pragma unroll
    for (int u = 0; u < HID/4; ++u) ((float4*)w)[u] = wr[u];
  }
  const float bias = b_ih[g] + b_hh[g];
  const float wih  = W_ih[g];

  if (g == 0) s_fz = TSEQ;
  __syncthreads();
  if (g < TSEQ) {
    float v = x[(size_t)n * TSEQ + g];
    s_x[g] = v;
    if (v == 0.0f) atomicMin(&s_fz, g);   // first zero index
  }
  if (g < HID) s_h[g] = 0.0f;
  __syncthreads();

  // reference: maxes==0 -> len=T, else first_zero+1
  const int fz  = s_fz;
  const int len = (fz == 0 || fz >= TSEQ) ? TSEQ : (fz + 1);

  const int gtype = g >> 7;   // 0:i 1:f 2:g(tanh) 3:o  (wave-uniform)
  float c = 0.0f;             // cell state for hidden unit g (threads g<128)
  float* __restrict__ hrow = hs + (size_t)n * TSEQ * HID;

  for (int t = 0; t < len; ++t) {
    // gate pre-activation: bias + wih*x_t + <h, W_hh[g,:]>
    float a0 = fmaf(wih, s_x[t], bias);
    float a1 = 0.f, a2 = 0.f, a3 = 0.f;   // 4 accumulators: break dep chain
    const float4* h4 = (const float4*)s_h;
    #pragma unroll
    for (int u = 0; u < HID/4; ++u) {
      float4 hv = h4[u];                  // same-address broadcast read
      a0 = fmaf(hv.x, w[4*u+0], a0);
      a1 = fmaf(hv.y, w[4*u+1], a1);
      a2 = fmaf(hv.z, w[4*u+2], a2);
      a3 = fmaf(hv.w, w[4*u+3], a3);
    }
    float a = (a0 + a1) + (a2 + a3);
    // per-gate nonlinearity on all 512 threads (branch is wave-uniform)
    float act = (gtype == 2) ? tanhf(a) : (1.0f / (1.0f + expf(-a)));
    s_g[g] = act;
    __syncthreads();
    if (g < HID) {
      float I = s_g[g], F = s_g[HID+g], Gg = s_g[2*HID+g], O = s_g[3*HID+g];
      c = fmaf(F, c, I * Gg);
      float h = O * tanhf(c);
      s_h[g] = h;
      hrow[(size_t)t * HID + g] = h;      // coalesced 512B store
    }
    __syncthreads();
  }
  // zero masked tail (t >= len) so GEMM1 can run dense over full K
  for (int t = len; t < TSEQ; ++t)
    if (g < HID) hrow[(size_t)t * HID + g] = 0.0f;
}

// ---------------------------------------------------------------------------
// GEMM1: part[ks][n][i] = sum_{k in ks-slice} hs[n][k] * W1[i][k]
// Block = (16 seqs) x (64 i) x (K/8 slice); 256 threads = 32 i-pairs x 8 k-phases.
// hs chunk staged in LDS (broadcast reads, conflict-free); W1 streamed from
// global (L1/L2-hot, read once per n-tile). Phase-partials reduced via LDS.
// ---------------------------------------------------------------------------
__global__ __launch_bounds__(256) void gemm1_kernel(
    const float* __restrict__ hs,    // [NSEQ, KTOT]
    const float* __restrict__ W1,    // [64, KTOT]
    float* __restrict__ part)        // [KSPLIT, NSEQ, 64]
{
  const int blk   = blockIdx.x;            // 0 .. 80*KSPLIT-1
  const int ntile = blk / KSPLIT;
  const int ks    = blk % KSPLIT;
  const int n0    = ntile * NT;
  const int kbase = ks * KPB;
  const int tid = threadIdx.x;
  const int ig  = tid & 31;                // i-pair group
  const int i0  = ig * 2;
  const int p   = tid >> 5;                // k4 phase 0..7

  __shared__ float s_hs[NT][KCH];          // 8 KB
  __shared__ float s_red[8][NT][64];       // 32 KB

  float acc[2][NT];
  #pragma unroll
  for (int ii = 0; ii < 2; ++ii)
    #pragma unroll
    for (int r = 0; r < NT; ++r) acc[ii][r] = 0.f;

  const float* w1a = W1 + (size_t)i0 * KTOT;
  const float* w1b = W1 + (size_t)(i0 + 1) * KTOT;

  for (int kc = 0; kc < KPB; kc += KCH) {
    const int k0 = kbase + kc;
    __syncthreads();
    #pragma unroll
    for (int u = 0; u < 2; ++u) {          // stage 16x128 floats, coalesced
      int v  = tid + u * 256;
      int r  = v >> 5;
      int cc = v & 31;
      ((float4*)&s_hs[r][0])[cc] =
          *(const float4*)(hs + (size_t)(n0 + r) * KTOT + k0 + cc * 4);
    }
    __syncthreads();
    #pragma unroll
    for (int u = 0; u < 4; ++u) {
      int k4 = p + u * 8;
      float4 wv0 = *(const float4*)(w1a + k0 + k4 * 4);
      float4 wv1 = *(const float4*)(w1b + k0 + k4 * 4);
      #pragma unroll
      for (int r = 0; r < NT; ++r) {
        float4 hv = ((const float4*)&s_hs[r][0])[k4];  // broadcast per phase
        acc[0][r] = fmaf(wv0.x, hv.x, acc[0][r]);
        acc[0][r] = fmaf(wv0.y, hv.y, acc[0][r]);
        acc[0][r] = fmaf(wv0.z, hv.z, acc[0][r]);
        acc[0][r] = fmaf(wv0.w, hv.w, acc[0][r]);
        acc[1][r] = fmaf(wv1.x, hv.x, acc[1][r]);
        acc[1][r] = fmaf(wv1.y, hv.y, acc[1][r]);
        acc[1][r] = fmaf(wv1.z, hv.z, acc[1][r]);
        acc[1][r] = fmaf(wv1.w, hv.w, acc[1][r]);
      }
    }
  }
  __syncthreads();
  #pragma unroll
  for (int ii = 0; ii < 2; ++ii)
    #pragma unroll
    for (int r = 0; r < NT; ++r)
      s_red[p][r][i0 + ii] = acc[ii][r];
  __syncthreads();
  #pragma unroll
  for (int u = 0; u < 4; ++u) {            // 1024 outputs / 256 threads
    int idx = tid + u * 256;
    int r = idx >> 6;
    int i = idx & 63;
    float v = 0.f;
    #pragma unroll
    for (int q = 0; q < 8; ++q) v += s_red[q][r][i];
    part[((size_t)ks * NSEQ + (n0 + r)) * 64 + i] = v;
  }
}

// ---------------------------------------------------------------------------
// GEMM2: out[b][m] = b2[m] + sum_k (b1[k&63] + sum_q part[q][b*20..][k]) * W2[m][k]
// 128 outputs total; single small block.
// ---------------------------------------------------------------------------
__global__ __launch_bounds__(128) void gemm2_kernel(
    const float* __restrict__ part,  // [KSPLIT, NSEQ, 64]
    const float* __restrict__ b1,    // [64]
    const float* __restrict__ W2,    // [2, 1280]
    const float* __restrict__ b2,    // [2]
    float* __restrict__ out)         // [64, 2]
{
  const int tid = threadIdx.x;
  const int b = tid >> 1;
  const int m = tid & 1;
  const float4* w4  = (const float4*)(W2 + (size_t)m * 1280);
  const float4* b14 = (const float4*)b1;
  float4 acc4 = {0.f, 0.f, 0.f, 0.f};
  for (int k4 = 0; k4 < 320; ++k4) {
    float4 f = b14[k4 & 15];
    #pragma unroll
    for (int q = 0; q < KSPLIT; ++q) {
      float4 pv = *(const float4*)(part + ((size_t)q * NSEQ + b * 20) * 64 + k4 * 4);
      f.x += pv.x; f.y += pv.y; f.z += pv.z; f.w += pv.w;
    }
    float4 wv = w4[k4];
    acc4.x = fmaf(f.x, wv.x, acc4.x);
    acc4.y = fmaf(f.y, wv.y, acc4.y);
    acc4.z = fmaf(f.z, wv.z, acc4.z);
    acc4.w = fmaf(f.w, wv.w, acc4.w);
  }
  out[b * 2 + m] = ((acc4.x + acc4.y) + (acc4.z + acc4.w)) + b2[m];
}

// ---------------------------------------------------------------------------
extern "C" void kernel_launch(void* const* d_in, const int* in_sizes, int n_in,
                              void* d_out, int out_size, void* d_ws, size_t ws_size,
                              hipStream_t stream) {
  const float* x    = (const float*)d_in[0];
  // d_in[1] = metadata: unused by the reference
  const float* W_ih = (const float*)d_in[2];
  const float* W_hh = (const float*)d_in[3];
  const float* b_ih = (const float*)d_in[4];
  const float* b_hh = (const float*)d_in[5];
  const float* W1   = (const float*)d_in[6];
  const float* b1   = (const float*)d_in[7];
  const float* W2   = (const float*)d_in[8];
  const float* b2   = (const float*)d_in[9];
  float* out = (float*)d_out;

  // workspace layout: hs [1280*28672] f32 (146.8 MB) + part [8*1280*64] f32 (2.6 MB)
  float* hs   = (float*)d_ws;
  float* part = hs + (size_t)NSEQ * KTOT;

  lstm_kernel<<<NSEQ, 512, 0, stream>>>(x, W_ih, W_hh, b_ih, b_hh, hs);
  gemm1_kernel<<<(NSEQ / NT) * KSPLIT, 256, 0, stream>>>(hs, W1, part);
  gemm2_kernel<<<1, 128, 0, stream>>>(part, b1, W2, b2, out);
}

// Round 2
// 1082.744 us; speedup vs baseline: 1.0646x; 1.0646x over previous
//
#include <hip/hip_runtime.h>
#include <cstdint>

// Problem constants (from reference)
#define TSEQ 224
#define HID 128
#define G4 512              // 4*HID gates
#define NSEQ 1280           // BATCHES*SUB = 64*20
#define KTOT (TSEQ*HID)     // 28672
#define NT 16               // sequences per GEMM1 block
#define KSPLIT 8            // K-split for GEMM1
#define KCH 128             // K staging chunk
#define KPB (KTOT/KSPLIT)   // 3584

__device__ __forceinline__ float fast_sigmoid(float a) {
  // 1/(1+e^-a); v_exp + v_rcp (~1e-6 rel err, fine vs 7.4e-4 threshold)
  float e = __expf(-a);
  return __builtin_amdgcn_rcpf(1.0f + e);
}
__device__ __forceinline__ float fast_tanh(float a) {
  // tanh(a) = 2*sigmoid(2a)-1; saturates correctly at +/-inf exp
  float e = __expf(-2.0f * a);
  return fmaf(2.0f, __builtin_amdgcn_rcpf(1.0f + e), -1.0f);
}

// ---------------------------------------------------------------------------
// LSTM: one block per sequence, 512 threads (thread g owns gate g, W_hh row g
// resident in 128 VGPRs — launch_bounds(512,2) raises the VGPR cap to 256 so
// the compiler keeps wv[] in registers instead of re-streaming W_hh from L2,
// which was the R0 bottleneck at ~45 TB/s demanded vs 34.5 TB/s L2 ceiling).
// Early-exits at ragged len; zero-fills hs tail.
// ---------------------------------------------------------------------------
__global__ __launch_bounds__(512, 2) void lstm_kernel(
    const float* __restrict__ x,      // [NSEQ, TSEQ]
    const float* __restrict__ W_ih,   // [512, 1]
    const float* __restrict__ W_hh,   // [512, 128]
    const float* __restrict__ b_ih,   // [512]
    const float* __restrict__ b_hh,   // [512]
    float* __restrict__ hs)           // [NSEQ, TSEQ, HID]
{
  const int n = blockIdx.x;
  const int g = threadIdx.x;

  __shared__ float s_x[TSEQ];
  __shared__ float s_h[HID];
  __shared__ float s_g[G4];
  __shared__ int   s_fz;

  // W_hh row g -> 32 float4 = 128 VGPRs (resident for the whole kernel)
  float4 wv[32];
  {
    const float4* wr = (const float4*)(W_hh + (size_t)g * HID);
    #pragma unroll
    for (int u = 0; u < 32; ++u) wv[u] = wr[u];
  }
  const float bias = b_ih[g] + b_hh[g];
  const float wih  = W_ih[g];

  if (g == 0) s_fz = TSEQ;
  __syncthreads();
  if (g < TSEQ) {
    float v = x[(size_t)n * TSEQ + g];
    s_x[g] = v;
    if (v == 0.0f) atomicMin(&s_fz, g);   // first zero index
  }
  if (g < HID) s_h[g] = 0.0f;
  __syncthreads();

  // reference: maxes==0 -> len=T, else first_zero+1
  const int fz  = s_fz;
  const int len = (fz == 0 || fz >= TSEQ) ? TSEQ : (fz + 1);

  const int gtype = g >> 7;   // 0:i 1:f 2:g(tanh) 3:o  (wave-uniform)
  float c = 0.0f;             // cell state for hidden unit g (threads g<128)
  float* __restrict__ hrow = hs + (size_t)n * TSEQ * HID;

  for (int t = 0; t < len; ++t) {
    // gate pre-activation: bias + wih*x_t + <h, W_hh[g,:]>
    float a0 = fmaf(wih, s_x[t], bias);
    float a1 = 0.f, a2 = 0.f, a3 = 0.f;   // 4 accumulators: break dep chain
    const float4* h4 = (const float4*)s_h;
    #pragma unroll
    for (int u = 0; u < 32; ++u) {
      float4 hv = h4[u];                  // same-address broadcast read
      a0 = fmaf(hv.x, wv[u].x, a0);
      a1 = fmaf(hv.y, wv[u].y, a1);
      a2 = fmaf(hv.z, wv[u].z, a2);
      a3 = fmaf(hv.w, wv[u].w, a3);
    }
    float a = (a0 + a1) + (a2 + a3);
    // per-gate nonlinearity on all 512 threads (branch is wave-uniform)
    float act = (gtype == 2) ? fast_tanh(a) : fast_sigmoid(a);
    s_g[g] = act;
    __syncthreads();
    if (g < HID) {
      float I = s_g[g], F = s_g[HID+g], Gg = s_g[2*HID+g], O = s_g[3*HID+g];
      c = fmaf(F, c, I * Gg);
      float h = O * fast_tanh(c);
      s_h[g] = h;
      hrow[(size_t)t * HID + g] = h;      // coalesced 512B store
    }
    __syncthreads();
  }
  // zero masked tail (t >= len) so GEMM1 can run dense over full K
  for (int t = len; t < TSEQ; ++t)
    if (g < HID) hrow[(size_t)t * HID + g] = 0.0f;
}

// ---------------------------------------------------------------------------
// GEMM1: part[ks][n][i] = sum_{k in ks-slice} hs[n][k] * W1[i][k]
// Block = (16 seqs) x (64 i) x (K/8 slice); 256 threads = 32 i-pairs x 8 k-phases.
// hs chunk staged in LDS (broadcast reads, conflict-free); W1 streamed from
// global (L1/L2-hot, read once per n-tile). Phase-partials reduced via LDS.
// ---------------------------------------------------------------------------
__global__ __launch_bounds__(256) void gemm1_kernel(
    const float* __restrict__ hs,    // [NSEQ, KTOT]
    const float* __restrict__ W1,    // [64, KTOT]
    float* __restrict__ part)        // [KSPLIT, NSEQ, 64]
{
  const int blk   = blockIdx.x;            // 0 .. 80*KSPLIT-1
  const int ntile = blk / KSPLIT;
  const int ks    = blk % KSPLIT;
  const int n0    = ntile * NT;
  const int kbase = ks * KPB;
  const int tid = threadIdx.x;
  const int ig  = tid & 31;                // i-pair group
  const int i0  = ig * 2;
  const int p   = tid >> 5;                // k4 phase 0..7

  __shared__ float s_hs[NT][KCH];          // 8 KB
  __shared__ float s_red[8][NT][64];       // 32 KB

  float acc[2][NT];
  #pragma unroll
  for (int ii = 0; ii < 2; ++ii)
    #pragma unroll
    for (int r = 0; r < NT; ++r) acc[ii][r] = 0.f;

  const float* w1a = W1 + (size_t)i0 * KTOT;
  const float* w1b = W1 + (size_t)(i0 + 1) * KTOT;

  for (int kc = 0; kc < KPB; kc += KCH) {
    const int k0 = kbase + kc;
    __syncthreads();
    #pragma unroll
    for (int u = 0; u < 2; ++u) {          // stage 16x128 floats, coalesced
      int v  = tid + u * 256;
      int r  = v >> 5;
      int cc = v & 31;
      ((float4*)&s_hs[r][0])[cc] =
          *(const float4*)(hs + (size_t)(n0 + r) * KTOT + k0 + cc * 4);
    }
    __syncthreads();
    #pragma unroll
    for (int u = 0; u < 4; ++u) {
      int k4 = p + u * 8;
      float4 wv0 = *(const float4*)(w1a + k0 + k4 * 4);
      float4 wv1 = *(const float4*)(w1b + k0 + k4 * 4);
      #pragma unroll
      for (int r = 0; r < NT; ++r) {
        float4 hv = ((const float4*)&s_hs[r][0])[k4];  // broadcast per phase
        acc[0][r] = fmaf(wv0.x, hv.x, acc[0][r]);
        acc[0][r] = fmaf(wv0.y, hv.y, acc[0][r]);
        acc[0][r] = fmaf(wv0.z, hv.z, acc[0][r]);
        acc[0][r] = fmaf(wv0.w, hv.w, acc[0][r]);
        acc[1][r] = fmaf(wv1.x, hv.x, acc[1][r]);
        acc[1][r] = fmaf(wv1.y, hv.y, acc[1][r]);
        acc[1][r] = fmaf(wv1.z, hv.z, acc[1][r]);
        acc[1][r] = fmaf(wv1.w, hv.w, acc[1][r]);
      }
    }
  }
  __syncthreads();
  #pragma unroll
  for (int ii = 0; ii < 2; ++ii)
    #pragma unroll
    for (int r = 0; r < NT; ++r)
      s_red[p][r][i0 + ii] = acc[ii][r];
  __syncthreads();
  #pragma unroll
  for (int u = 0; u < 4; ++u) {            // 1024 outputs / 256 threads
    int idx = tid + u * 256;
    int r = idx >> 6;
    int i = idx & 63;
    float v = 0.f;
    #pragma unroll
    for (int q = 0; q < 8; ++q) v += s_red[q][r][i];
    part[((size_t)ks * NSEQ + (n0 + r)) * 64 + i] = v;
  }
}

// ---------------------------------------------------------------------------
// GEMM2: out[b][m] = b2[m] + sum_k (b1[k&63] + sum_q part[q][b*20..][k]) * W2[m][k]
// 128 outputs total; single small block.
// ---------------------------------------------------------------------------
__global__ __launch_bounds__(128) void gemm2_kernel(
    const float* __restrict__ part,  // [KSPLIT, NSEQ, 64]
    const float* __restrict__ b1,    // [64]
    const float* __restrict__ W2,    // [2, 1280]
    const float* __restrict__ b2,    // [2]
    float* __restrict__ out)         // [64, 2]
{
  const int tid = threadIdx.x;
  const int b = tid >> 1;
  const int m = tid & 1;
  const float4* w4  = (const float4*)(W2 + (size_t)m * 1280);
  const float4* b14 = (const float4*)b1;
  float4 acc4 = {0.f, 0.f, 0.f, 0.f};
  for (int k4 = 0; k4 < 320; ++k4) {
    float4 f = b14[k4 & 15];
    #pragma unroll
    for (int q = 0; q < KSPLIT; ++q) {
      float4 pv = *(const float4*)(part + ((size_t)q * NSEQ + b * 20) * 64 + k4 * 4);
      f.x += pv.x; f.y += pv.y; f.z += pv.z; f.w += pv.w;
    }
    float4 wv = w4[k4];
    acc4.x = fmaf(f.x, wv.x, acc4.x);
    acc4.y = fmaf(f.y, wv.y, acc4.y);
    acc4.z = fmaf(f.z, wv.z, acc4.z);
    acc4.w = fmaf(f.w, wv.w, acc4.w);
  }
  out[b * 2 + m] = ((acc4.x + acc4.y) + (acc4.z + acc4.w)) + b2[m];
}

// ---------------------------------------------------------------------------
extern "C" void kernel_launch(void* const* d_in, const int* in_sizes, int n_in,
                              void* d_out, int out_size, void* d_ws, size_t ws_size,
                              hipStream_t stream) {
  const float* x    = (const float*)d_in[0];
  // d_in[1] = metadata: unused by the reference
  const float* W_ih = (const float*)d_in[2];
  const float* W_hh = (const float*)d_in[3];
  const float* b_ih = (const float*)d_in[4];
  const float* b_hh = (const float*)d_in[5];
  const float* W1   = (const float*)d_in[6];
  const float* b1   = (const float*)d_in[7];
  const float* W2   = (const float*)d_in[8];
  const float* b2   = (const float*)d_in[9];
  float* out = (float*)d_out;

  // workspace layout: hs [1280*28672] f32 (146.8 MB) + part [8*1280*64] f32 (2.6 MB)
  float* hs   = (float*)d_ws;
  float* part = hs + (size_t)NSEQ * KTOT;

  lstm_kernel<<<NSEQ, 512, 0, stream>>>(x, W_ih, W_hh, b_ih, b_hh, hs);
  gemm1_kernel<<<(NSEQ / NT) * KSPLIT, 256, 0, stream>>>(hs, W1, part);
  gemm2_kernel<<<1, 128, 0, stream>>>(part, b1, W2, b2, out);
}